// Round 10
// baseline (429.744 us; speedup 1.0000x reference)
//
#include <hip/hip_runtime.h>

// Problem constants
constexpr int Bb  = 16;
constexpr int Dd  = 128;
constexpr int Tt  = 2048;
constexpr int NQn = 8;
constexpr int CSc = 1024;

constexpr int TB   = 64;    // t per block (2 tiles x 32)
constexpr int NCHQ = 16;    // 32-code chunks per half per quantizer
constexpr int CHH  = 8192;  // _Float16 per chunk: 32 codes * 128 d * 2 planes (16 KB)

typedef _Float16 half8 __attribute__((ext_vector_type(8)));
typedef __attribute__((ext_vector_type(4)))  float f32x4;
typedef __attribute__((ext_vector_type(16))) float f32x16;

// ---- scaled f16 2-plane split: x ~= H + M'*2^-12 (~22 mantissa bits) ----
// |x| < 2^-14 forces H=0 so the MFMA never sees a subnormal H; M' = f16(e*4096)
// is then normal and captures the value at full f16 precision.
__device__ inline void fsplit(float xv, _Float16& h, _Float16& m) {
    _Float16 hh = (__builtin_fabsf(xv) < 6.103515625e-05f) ? (_Float16)0.0f
                                                           : (_Float16)xv;
    float e = xv - (float)hh;
    h = hh;
    m = (_Float16)(e * 4096.0f);
}
__device__ inline float frec(_Float16 h, _Float16 m) {
    return fmaf((float)m, 2.44140625e-4f, (float)h);   // exact in fp32
}

// async global->LDS, 16 B/lane (LDS dest = wave-uniform base + lane*16)
__device__ inline void gload_lds16(const _Float16* g, _Float16* l) {
    __builtin_amdgcn_global_load_lds(
        (const __attribute__((address_space(1))) void*)g,
        (__attribute__((address_space(3))) void*)l, 16, 0, 0);
}

#define MFMAH(A, B, C) __builtin_amdgcn_mfma_f32_32x32x16_f16(A, B, C, 0, 0, 0)

// ---------------------------------------------------------------------------
// Kernel 0: split codebook fp32 -> 2 f16 planes (H, M'), fragment-ordered per
// 32-code chunk for mfma_32x32x16: record (p, ks, lane) holds
// code = chunk*32 + (lane&31), dims ks*16 + (lane>>5)*8 + j.
// Also exact fp32 ||c||^2 (same tree as rounds 5-9).
// ---------------------------------------------------------------------------
__global__ __launch_bounds__(64) void split_kernel(const float* __restrict__ cb,
                                                   _Float16* __restrict__ cbS,
                                                   float* __restrict__ cn) {
    const int c     = blockIdx.x * 64 + threadIdx.x;  // global code id
    const int chunk = c >> 5;
    const int c31   = c & 31;
    const float* p  = cb + (size_t)c * Dd;
    const size_t base = (size_t)chunk * CHH;

    float s0 = 0.f, s1 = 0.f, s2 = 0.f, s3 = 0.f;
#pragma unroll
    for (int ks = 0; ks < 8; ++ks) {
#pragma unroll
        for (int hi2 = 0; hi2 < 2; ++hi2) {
            const int lanew = hi2 * 32 + c31;
            half8 h8, m8;
#pragma unroll
            for (int jj = 0; jj < 8; jj += 4) {
                float4 v = *(const float4*)(p + ks * 16 + hi2 * 8 + jj);
                s0 = fmaf(v.x, v.x, s0);
                s1 = fmaf(v.y, v.y, s1);
                s2 = fmaf(v.z, v.z, s2);
                s3 = fmaf(v.w, v.w, s3);
                _Float16 hh, mm;
                fsplit(v.x, hh, mm); h8[jj + 0] = hh; m8[jj + 0] = mm;
                fsplit(v.y, hh, mm); h8[jj + 1] = hh; m8[jj + 1] = mm;
                fsplit(v.z, hh, mm); h8[jj + 2] = hh; m8[jj + 2] = mm;
                fsplit(v.w, hh, mm); h8[jj + 3] = hh; m8[jj + 3] = mm;
            }
            *(half8*)&cbS[base + (size_t)((0 * 8 + ks) * 64 + lanew) * 8] = h8;
            *(half8*)&cbS[base + (size_t)((8 + ks) * 64 + lanew) * 8]     = m8;
        }
    }
    cn[c] = (s0 + s1) + (s2 + s3);
}

// ---------------------------------------------------------------------------
// Kernel 1: MFMA RVQ. 256 threads = 4 waves = 2 t-tiles(32 t) x 2 code-halves.
// Grid 512 -> 2 independent blocks/CU (LDS ~71 KB): cross-block overlap fills
// each block's barrier/drain gaps. Residual = 2 f16 planes in registers.
// Per window: issue next chunk's staging EARLY, compute current chunk
// (24 MFMA, 3-pass scaled-f16), vmcnt(0)+raw barrier LATE. Math bit-identical
// to round 9.
// ---------------------------------------------------------------------------
__global__ __launch_bounds__(256) void rvq_mfma(const float* __restrict__ x,
                                                const float* __restrict__ cb,
                                                const _Float16* __restrict__ cbS,
                                                const float* __restrict__ cn_g,
                                                float* __restrict__ out,
                                                float* __restrict__ part) {
    __shared__ __align__(16) _Float16 sA[2][2][CHH];   // [dbuf][half] = 64 KB
    __shared__ __align__(16) float    cn_lds[CSc];     // 4 KB
    __shared__ float s_best[4][32];
    __shared__ int   s_idx[4][32];
    __shared__ float s_red[2];

    const int tid  = threadIdx.x;
    const int lane = tid & 63;
    const int w    = __builtin_amdgcn_readfirstlane(tid >> 6);
    const int tt   = w >> 1;          // t-tile 0..1
    const int h    = w & 1;           // code half
    const int l31  = lane & 31;       // t within tile / C-D column
    const int hi   = lane >> 5;       // k-subgroup 0..1

    const int t0  = blockIdx.x * TB;
    const int b   = t0 >> 11;
    const int tb0 = t0 & (Tt - 1);
    const int tg  = tb0 + tt * 32 + l31;
    const size_t xbase = (size_t)b * Dd * Tt;

    // ---- residual state: 2 f16 planes; lane owns dims ks*16+hi*8+j of t=tg
    half8 Bh[8], Bm[8];
    float rn;
    {
        float p0 = 0.f, p1 = 0.f, p2 = 0.f, p3 = 0.f;
#pragma unroll
        for (int ks = 0; ks < 8; ++ks) {
            half8 h8, m8;
#pragma unroll
            for (int j = 0; j < 8; ++j) {
                float v = x[xbase + (size_t)(ks * 16 + hi * 8 + j) * Tt + tg];
                _Float16 hh, mm;
                fsplit(v, hh, mm);
                h8[j] = hh; m8[j] = mm;
                if ((j & 3) == 0)      p0 = fmaf(v, v, p0);
                else if ((j & 3) == 1) p1 = fmaf(v, v, p1);
                else if ((j & 3) == 2) p2 = fmaf(v, v, p2);
                else                   p3 = fmaf(v, v, p3);
            }
            Bh[ks] = h8; Bm[ks] = m8;
        }
        float rnp = (p0 + p1) + (p2 + p3);
        rnp += __shfl_xor(rnp, 32, 64);
        rn = rnp;
    }

    float loss_acc = 0.f;

#pragma unroll 1
    for (int q = 0; q < NQn; ++q) {
        // stage ||c||^2 for this quantizer (256 threads x 16 B = 4 KB)
        *(f32x4*)&cn_lds[tid * 4] = *(const f32x4*)&cn_g[(size_t)q * CSc + tid * 4];

        // staging: wave w copies 8 KB of the 32-KB chunk pair
        //   half hh = w>>1, segment seg = w&1
        auto STAGE = [&](int ct, int bb) {
            const int hh = w >> 1, seg = w & 1;
            const int gc = q * 32 + hh * 16 + ct;
            const _Float16* g = cbS + (size_t)gc * CHH + seg * 4096 + lane * 8;
            _Float16* dl = &sA[bb][hh][seg * 4096];
#pragma unroll
            for (int i = 0; i < 8; ++i) gload_lds16(g + i * 512, dl + i * 512);
        };

        // prologue: chunk 0 -> buf 0; drain; barrier (cn_lds write also lands)
        STAGE(0, 0);
        asm volatile("s_waitcnt vmcnt(0) lgkmcnt(0)" ::: "memory");
        __builtin_amdgcn_s_barrier();
        asm volatile("" ::: "memory");

        float best = 3.4e38f;
        int   bidx = 0;

#pragma unroll 1
        for (int ct = 0; ct < NCHQ; ++ct) {
            // issue next chunk's staging EARLY (latency hides under compute)
            if (ct + 1 < NCHQ) STAGE(ct + 1, (ct + 1) & 1);

            // A-fragments: conflict-free lane-linear ds_read_b128
            const _Float16* ab = &sA[ct & 1][h][0];
            half8 Ah[8], Am[8];
#pragma unroll
            for (int ks = 0; ks < 8; ++ks) {
                Ah[ks] = *(const half8*)&ab[(size_t)((0 * 8 + ks) * 64 + lane) * 8];
                Am[ks] = *(const half8*)&ab[(size_t)((8 + ks) * 64 + lane) * 8];
            }

            f32x16 accA  = {0.f,0.f,0.f,0.f,0.f,0.f,0.f,0.f,0.f,0.f,0.f,0.f,0.f,0.f,0.f,0.f};
            f32x16 accB1 = accA, accB2 = accA;
            __builtin_amdgcn_s_setprio(1);
#pragma unroll
            for (int ks = 0; ks < 8; ++ks) {
                accA  = MFMAH(Ah[ks], Bh[ks], accA);    // H_c * H_r
                accB1 = MFMAH(Ah[ks], Bm[ks], accB1);   // H_c * M'_r  (2^12-scaled)
                accB2 = MFMAH(Am[ks], Bh[ks], accB2);   // M'_c * H_r  (2^12-scaled)
            }
            __builtin_amdgcn_s_setprio(0);

            const int cq = h * 512 + ct * 32;
#pragma unroll
            for (int blk = 0; blk < 4; ++blk) {
                f32x4 cn4 = *(const f32x4*)&cn_lds[cq + blk * 8 + hi * 4];
#pragma unroll
                for (int e = 0; e < 4; ++e) {
                    const int i = blk * 4 + e;
                    // dot = accA + 2^-12 (accB1 + accB2)
                    float dotv = fmaf(accB1[i] + accB2[i], 2.44140625e-4f, accA[i]);
                    // C/D: code = (reg&3)+8*(reg>>2)+4*hi, col = t  (r7-verified)
                    float dd = fmaf(-2.f, dotv, rn + cn4[e]);
                    int cid = cq + blk * 8 + hi * 4 + e;
                    if (dd < best) { best = dd; bidx = cid; }   // strict <
                }
            }

            // wait LATE: the staging issued at window start has had ~a full
            // window of compute to land; sibling block hides the remainder.
            asm volatile("s_waitcnt vmcnt(0)" ::: "memory");
            __builtin_amdgcn_s_barrier();
            asm volatile("" ::: "memory");
        }

        // ---- argmin: combine two k-subgroups (same t), lexicographic ----
        {
            float ob = __shfl_xor(best, 32, 64);
            int   oi = __shfl_xor(bidx, 32, 64);
            if (ob < best || (ob == best && oi < bidx)) { best = ob; bidx = oi; }
        }
        if (hi == 0) { s_best[w][l31] = best; s_idx[w][l31] = bidx; }
        __syncthreads();
        // combine with partner half (lex -> lowest index wins ties)
        {
            float ob = s_best[w ^ 1][l31];
            int   oi = s_idx[w ^ 1][l31];
            if (ob < best || (ob == best && oi < bidx)) { best = ob; bidx = oi; }
        }
        const int g = bidx;

        // ---- residual update: reconstruct H+M'*2^-12, subtract fp32 code,
        //      re-split; accumulate loss = ||r_new||^2 ----
        {
            const float* cp = cb + ((size_t)q * CSc + g) * Dd + hi * 8;
            float q0 = 0.f, q1 = 0.f, q2 = 0.f, q3 = 0.f;
#pragma unroll
            for (int ks = 0; ks < 8; ++ks) {
                f32x4 ca  = *(const f32x4*)(cp + ks * 16);
                f32x4 cb4 = *(const f32x4*)(cp + ks * 16 + 4);
                half8 h8 = Bh[ks], m8 = Bm[ks];
                half8 nh, nm;
#pragma unroll
                for (int j = 0; j < 8; ++j) {
                    float cj = (j < 4) ? ca[j] : cb4[j - 4];
                    float nv = frec(h8[j], m8[j]) - cj;
                    if ((j & 3) == 0)      q0 = fmaf(nv, nv, q0);
                    else if ((j & 3) == 1) q1 = fmaf(nv, nv, q1);
                    else if ((j & 3) == 2) q2 = fmaf(nv, nv, q2);
                    else                   q3 = fmaf(nv, nv, q3);
                    _Float16 hh, mm;
                    fsplit(nv, hh, mm);
                    nh[j] = hh; nm[j] = mm;
                }
                Bh[ks] = nh; Bm[ks] = nm;
            }
            float rnn = (q0 + q1) + (q2 + q3);
            rnn += __shfl_xor(rnn, 32, 64);
            rn = rnn;                       // ||r||^2 for next stage
            if (h == 0) loss_acc += rnn;    // both hi lanes count -> x2
        }
    }

    // ---- epilogue: q_sum = x0 - r_final (h==0 waves; state identical) ----
    if (h == 0) {
#pragma unroll
        for (int ks = 0; ks < 8; ++ks) {
            half8 h8 = Bh[ks], m8 = Bm[ks];
#pragma unroll
            for (int j = 0; j < 8; ++j) {
                size_t off = xbase + (size_t)(ks * 16 + hi * 8 + j) * Tt + tg;
                out[off] = x[off] - frec(h8[j], m8[j]);
            }
        }
        float ls = loss_acc;
#pragma unroll
        for (int off = 32; off > 0; off >>= 1) ls += __shfl_down(ls, off, 64);
        if (lane == 0) s_red[tt] = ls;
    }
    __syncthreads();
    if (tid == 0)
        part[blockIdx.x] = 0.5f * (s_red[0] + s_red[1]);
}

// ---------------------------------------------------------------------------
// Kernel 2: deterministic loss reduction (32 block-partials per batch element)
// ---------------------------------------------------------------------------
__global__ __launch_bounds__(64) void loss_kernel(const float* __restrict__ part,
                                                  float* __restrict__ out_loss) {
    int b = threadIdx.x;
    if (b < Bb) {
        float s = 0.f;
        const int ppb = Tt / TB;  // 32
        for (int k = 0; k < ppb; ++k) s += part[b * ppb + k];
        out_loss[b] = s * (1.0f / ((float)Dd * (float)Tt));
    }
}

// ---------------------------------------------------------------------------
extern "C" void kernel_launch(void* const* d_in, const int* in_sizes, int n_in,
                              void* d_out, int out_size, void* d_ws, size_t ws_size,
                              hipStream_t stream) {
    const float* x  = (const float*)d_in[0];   // [B, D, T]
    const float* cb = (const float*)d_in[1];   // [NQ, CS, D]
    float* out = (float*)d_out;                // [B*D*T] q_sum ++ [B] loss_sum

    // workspace: cn[8192] f32 | part[512] f32 | cbS 2-plane f16 (4 MB)
    float*    cn   = (float*)d_ws;
    float*    part = cn + NQn * CSc;
    _Float16* cbS  = (_Float16*)(part + 512);

    split_kernel<<<(NQn * CSc) / 64, 64, 0, stream>>>(cb, cbS, cn);

    const int nblocks = (Bb * Tt) / TB;  // 512
    rvq_mfma<<<nblocks, 256, 0, stream>>>(x, cb, cbS, cn, out, part);

    loss_kernel<<<1, 64, 0, stream>>>(part, out + (size_t)Bb * Dd * Tt);
}

// Round 11
// 291.320 us; speedup vs baseline: 1.4752x; 1.4752x over previous
//
#include <hip/hip_runtime.h>

// Problem constants
constexpr int Bb  = 16;
constexpr int Dd  = 128;
constexpr int Tt  = 2048;
constexpr int NQn = 8;
constexpr int CSc = 1024;

constexpr int TB   = 128;   // t per block
constexpr int NCHQ = 16;    // 32-code chunks per half per quantizer
constexpr int CHH  = 8192;  // _Float16 per chunk: 32 codes * 128 d * 2 planes (16 KB)

typedef _Float16 half8 __attribute__((ext_vector_type(8)));
typedef __attribute__((ext_vector_type(4)))  float f32x4;
typedef __attribute__((ext_vector_type(16))) float f32x16;

// ---- scaled f16 2-plane split: x ~= H + M'*2^-12 (~22 mantissa bits) ----
__device__ inline void fsplit(float xv, _Float16& h, _Float16& m) {
    _Float16 hh = (__builtin_fabsf(xv) < 6.103515625e-05f) ? (_Float16)0.0f
                                                           : (_Float16)xv;
    float e = xv - (float)hh;
    h = hh;
    m = (_Float16)(e * 4096.0f);
}
__device__ inline float frec(_Float16 h, _Float16 m) {
    return fmaf((float)m, 2.44140625e-4f, (float)h);   // exact in fp32
}

// async global->LDS, 16 B/lane (LDS dest = wave-uniform base + lane*16)
__device__ inline void gload_lds16(const _Float16* g, _Float16* l) {
    __builtin_amdgcn_global_load_lds(
        (const __attribute__((address_space(1))) void*)g,
        (__attribute__((address_space(3))) void*)l, 16, 0, 0);
}

#define MFMAH(A, B, C) __builtin_amdgcn_mfma_f32_32x32x16_f16(A, B, C, 0, 0, 0)

// ---------------------------------------------------------------------------
// Kernel 0: split codebook fp32 -> 2 f16 planes (H, M'), fragment-ordered per
// 32-code chunk for mfma_32x32x16 (layout identical to round 9).
// Also exact fp32 ||c||^2.
// ---------------------------------------------------------------------------
__global__ __launch_bounds__(64) void split_kernel(const float* __restrict__ cb,
                                                   _Float16* __restrict__ cbS,
                                                   float* __restrict__ cn) {
    const int c     = blockIdx.x * 64 + threadIdx.x;  // global code id
    const int chunk = c >> 5;
    const int c31   = c & 31;
    const float* p  = cb + (size_t)c * Dd;
    const size_t base = (size_t)chunk * CHH;

    float s0 = 0.f, s1 = 0.f, s2 = 0.f, s3 = 0.f;
#pragma unroll
    for (int ks = 0; ks < 8; ++ks) {
#pragma unroll
        for (int hi2 = 0; hi2 < 2; ++hi2) {
            const int lanew = hi2 * 32 + c31;
            half8 h8, m8;
#pragma unroll
            for (int jj = 0; jj < 8; jj += 4) {
                float4 v = *(const float4*)(p + ks * 16 + hi2 * 8 + jj);
                s0 = fmaf(v.x, v.x, s0);
                s1 = fmaf(v.y, v.y, s1);
                s2 = fmaf(v.z, v.z, s2);
                s3 = fmaf(v.w, v.w, s3);
                _Float16 hh, mm;
                fsplit(v.x, hh, mm); h8[jj + 0] = hh; m8[jj + 0] = mm;
                fsplit(v.y, hh, mm); h8[jj + 1] = hh; m8[jj + 1] = mm;
                fsplit(v.z, hh, mm); h8[jj + 2] = hh; m8[jj + 2] = mm;
                fsplit(v.w, hh, mm); h8[jj + 3] = hh; m8[jj + 3] = mm;
            }
            *(half8*)&cbS[base + (size_t)((0 * 8 + ks) * 64 + lanew) * 8] = h8;
            *(half8*)&cbS[base + (size_t)((8 + ks) * 64 + lanew) * 8]     = m8;
        }
    }
    cn[c] = (s0 + s1) + (s2 + s3);
}

// ---------------------------------------------------------------------------
// Kernel 1: MFMA RVQ. 512 threads = 8 waves = 4 t-tiles(32 t) x 2 code-halves
// (round-9 geometry, 1 block/CU). NEW: T15 double-state accumulators — the
// dist-eval of chunk e runs while chunk e+1's MFMAs occupy the matrix pipe;
// merged accB chain; dist' = cn/2 - dot; 4-buffer ring + counted vmcnt(4).
// ---------------------------------------------------------------------------
__global__ __launch_bounds__(512) void rvq_mfma(const float* __restrict__ x,
                                                const float* __restrict__ cb,
                                                const _Float16* __restrict__ cbS,
                                                const float* __restrict__ cn_g,
                                                float* __restrict__ out,
                                                float* __restrict__ part) {
    __shared__ __align__(16) _Float16 sA[4][2][CHH];   // 128 KB ring
    __shared__ __align__(16) float    cn_lds[CSc];     // holds 0.5*||c||^2
    __shared__ float s_best[8][32];
    __shared__ int   s_idx[8][32];
    __shared__ float s_red[4];

    const int tid  = threadIdx.x;
    const int lane = tid & 63;
    const int w    = __builtin_amdgcn_readfirstlane(tid >> 6);
    const int tt   = w >> 1;          // t-tile 0..3
    const int h    = w & 1;           // code half
    const int l31  = lane & 31;       // t within tile / C-D column
    const int hi   = lane >> 5;       // k-subgroup 0..1

    const int t0  = blockIdx.x * TB;
    const int b   = t0 >> 11;
    const int tb0 = t0 & (Tt - 1);
    const int tg  = tb0 + tt * 32 + l31;
    const size_t xbase = (size_t)b * Dd * Tt;

    // ---- residual state: 2 f16 planes; lane owns dims ks*16+hi*8+j of t=tg
    half8 Bh[8], Bm[8];
    float rn;
    {
        float p0 = 0.f, p1 = 0.f, p2 = 0.f, p3 = 0.f;
#pragma unroll
        for (int ks = 0; ks < 8; ++ks) {
            half8 h8, m8;
#pragma unroll
            for (int j = 0; j < 8; ++j) {
                float v = x[xbase + (size_t)(ks * 16 + hi * 8 + j) * Tt + tg];
                _Float16 hh, mm;
                fsplit(v, hh, mm);
                h8[j] = hh; m8[j] = mm;
                if ((j & 3) == 0)      p0 = fmaf(v, v, p0);
                else if ((j & 3) == 1) p1 = fmaf(v, v, p1);
                else if ((j & 3) == 2) p2 = fmaf(v, v, p2);
                else                   p3 = fmaf(v, v, p3);
            }
            Bh[ks] = h8; Bm[ks] = m8;
        }
        float rnp = (p0 + p1) + (p2 + p3);
        rnp += __shfl_xor(rnp, 32, 64);
        rn = rnp;
    }

    float loss_acc = 0.f;

#pragma unroll 1
    for (int q = 0; q < NQn; ++q) {
        // stage 0.5*||c||^2 for this quantizer (512 threads x 8 B)
        {
            float2 c2 = *(const float2*)&cn_g[(size_t)q * CSc + tid * 2];
            c2.x *= 0.5f; c2.y *= 0.5f;
            *(float2*)&cn_lds[tid * 2] = c2;
        }

        // staging: wave w copies 4 KB of its half's 16-KB chunk
        auto STAGE = [&](int ct, int bb) {
            const int gc = q * 32 + h * 16 + ct;
            const _Float16* g = cbS + (size_t)gc * CHH + tt * 2048 + lane * 8;
            _Float16* dl = &sA[bb][h][tt * 2048];
#pragma unroll
            for (int i = 0; i < 4; ++i) gload_lds16(g + i * 512, dl + i * 512);
        };

        // prologue: chunks 0,1 -> bufs 0,1; wait chunk 0 (chunk 1 in flight)
        STAGE(0, 0);
        STAGE(1, 1);
        asm volatile("s_waitcnt vmcnt(4) lgkmcnt(0)" ::: "memory");
        __builtin_amdgcn_s_barrier();
        asm volatile("" ::: "memory");

        float best = 3.4e38f;
        int   bidx = 0;
        f32x16 aA0, aB0, aA1, aB1;   // two named acc sets (even/odd chunks)

#define DO_MFMA(E, AA, AB)                                                     \
        {                                                                      \
            const _Float16* ab = &sA[(E) & 3][h][0];                           \
            AA = (f32x16){0.f,0.f,0.f,0.f,0.f,0.f,0.f,0.f,                     \
                          0.f,0.f,0.f,0.f,0.f,0.f,0.f,0.f};                    \
            AB = AA;                                                           \
            __builtin_amdgcn_s_setprio(1);                                     \
            _Pragma("unroll")                                                  \
            for (int ks = 0; ks < 8; ++ks) {                                   \
                half8 Ah = *(const half8*)&ab[(size_t)((ks)*64 + lane) * 8];   \
                half8 Am = *(const half8*)&ab[(size_t)((8+ks)*64 + lane) * 8]; \
                AA = MFMAH(Ah, Bh[ks], AA);          /* H_c * H_r        */    \
                AB = MFMAH(Ah, Bm[ks], AB);          /* H_c * M'_r       */    \
                AB = MFMAH(Am, Bh[ks], AB);          /* M'_c * H_r       */    \
            }                                                                  \
            __builtin_amdgcn_s_setprio(0);                                     \
        }

#define DO_EVAL(E, AA, AB)                                                     \
        {                                                                      \
            const int cq = h * 512 + (E) * 32;                                 \
            _Pragma("unroll")                                                  \
            for (int blk = 0; blk < 4; ++blk) {                                \
                f32x4 ch4 = *(const f32x4*)&cn_lds[cq + blk * 8 + hi * 4];     \
                _Pragma("unroll")                                              \
                for (int e2 = 0; e2 < 4; ++e2) {                               \
                    const int i = blk * 4 + e2;                                \
                    float dotv = fmaf(AB[i], 2.44140625e-4f, AA[i]);           \
                    float s = ch4[e2] - dotv;      /* dist' = cn/2 - dot */    \
                    int cid = cq + blk * 8 + hi * 4 + e2;                      \
                    if (s < best) { best = s; bidx = cid; }   /* strict < */   \
                }                                                              \
            }                                                                  \
        }

#pragma unroll 1
        for (int it = 0; it < 8; ++it) {
            const int e0 = 2 * it, e1 = 2 * it + 1;

            // ---- even chunk: MFMA(e0) overlaps EVAL(e0-1) ----
            if (it < 7) STAGE(e0 + 2, (e0 + 2) & 3);
            DO_MFMA(e0, aA0, aB0);
            if (it > 0) DO_EVAL(e0 - 1, aA1, aB1);
            if (it < 7) asm volatile("s_waitcnt vmcnt(4)" ::: "memory");
            else        asm volatile("s_waitcnt vmcnt(0)" ::: "memory");
            __builtin_amdgcn_s_barrier();
            asm volatile("" ::: "memory");

            // ---- odd chunk: MFMA(e1) overlaps EVAL(e0) ----
            if (it < 7) STAGE(e1 + 2, (e1 + 2) & 3);
            DO_MFMA(e1, aA1, aB1);
            DO_EVAL(e0, aA0, aB0);
            if (it < 7) asm volatile("s_waitcnt vmcnt(4)" ::: "memory");
            else        asm volatile("s_waitcnt vmcnt(0)" ::: "memory");
            __builtin_amdgcn_s_barrier();
            asm volatile("" ::: "memory");
        }
        DO_EVAL(15, aA1, aB1);   // drain the last deferred eval

#undef DO_MFMA
#undef DO_EVAL

        // ---- argmin: combine two k-subgroups (same t), lexicographic ----
        {
            float ob = __shfl_xor(best, 32, 64);
            int   oi = __shfl_xor(bidx, 32, 64);
            if (ob < best || (ob == best && oi < bidx)) { best = ob; bidx = oi; }
        }
        if (hi == 0) { s_best[w][l31] = best; s_idx[w][l31] = bidx; }
        __syncthreads();   // also orders EVAL(15) reads before next q's cn_lds write
        // combine with partner half (lex -> lowest index wins ties)
        {
            float ob = s_best[w ^ 1][l31];
            int   oi = s_idx[w ^ 1][l31];
            if (ob < best || (ob == best && oi < bidx)) { best = ob; bidx = oi; }
        }
        const int g = bidx;

        // ---- residual update: reconstruct H+M'*2^-12, subtract fp32 code,
        //      re-split; accumulate loss = ||r_new||^2 (verbatim round 9) ----
        {
            const float* cp = cb + ((size_t)q * CSc + g) * Dd + hi * 8;
            float q0 = 0.f, q1 = 0.f, q2 = 0.f, q3 = 0.f;
#pragma unroll
            for (int ks = 0; ks < 8; ++ks) {
                f32x4 ca  = *(const f32x4*)(cp + ks * 16);
                f32x4 cb4 = *(const f32x4*)(cp + ks * 16 + 4);
                half8 h8 = Bh[ks], m8 = Bm[ks];
                half8 nh, nm;
#pragma unroll
                for (int j = 0; j < 8; ++j) {
                    float cj = (j < 4) ? ca[j] : cb4[j - 4];
                    float nv = frec(h8[j], m8[j]) - cj;
                    if ((j & 3) == 0)      q0 = fmaf(nv, nv, q0);
                    else if ((j & 3) == 1) q1 = fmaf(nv, nv, q1);
                    else if ((j & 3) == 2) q2 = fmaf(nv, nv, q2);
                    else                   q3 = fmaf(nv, nv, q3);
                    _Float16 hh, mm;
                    fsplit(nv, hh, mm);
                    nh[j] = hh; nm[j] = mm;
                }
                Bh[ks] = nh; Bm[ks] = nm;
            }
            float rnn = (q0 + q1) + (q2 + q3);
            rnn += __shfl_xor(rnn, 32, 64);
            rn = rnn;                       // ||r||^2 for next stage (loss only)
            if (h == 0) loss_acc += rnn;    // both hi lanes count -> x2
        }
    }

    // ---- epilogue: q_sum = x0 - r_final (h==0 waves; state identical) ----
    if (h == 0) {
#pragma unroll
        for (int ks = 0; ks < 8; ++ks) {
            half8 h8 = Bh[ks], m8 = Bm[ks];
#pragma unroll
            for (int j = 0; j < 8; ++j) {
                size_t off = xbase + (size_t)(ks * 16 + hi * 8 + j) * Tt + tg;
                out[off] = x[off] - frec(h8[j], m8[j]);
            }
        }
        float ls = loss_acc;
#pragma unroll
        for (int off = 32; off > 0; off >>= 1) ls += __shfl_down(ls, off, 64);
        if (lane == 0) s_red[tt] = ls;
    }
    __syncthreads();
    if (tid == 0)
        part[blockIdx.x] = 0.5f * ((s_red[0] + s_red[1]) + (s_red[2] + s_red[3]));
}

// ---------------------------------------------------------------------------
// Kernel 2: deterministic loss reduction (16 block-partials per batch element)
// ---------------------------------------------------------------------------
__global__ __launch_bounds__(64) void loss_kernel(const float* __restrict__ part,
                                                  float* __restrict__ out_loss) {
    int b = threadIdx.x;
    if (b < Bb) {
        float s = 0.f;
        const int ppb = Tt / TB;  // 16
        for (int k = 0; k < ppb; ++k) s += part[b * ppb + k];
        out_loss[b] = s * (1.0f / ((float)Dd * (float)Tt));
    }
}

// ---------------------------------------------------------------------------
extern "C" void kernel_launch(void* const* d_in, const int* in_sizes, int n_in,
                              void* d_out, int out_size, void* d_ws, size_t ws_size,
                              hipStream_t stream) {
    const float* x  = (const float*)d_in[0];   // [B, D, T]
    const float* cb = (const float*)d_in[1];   // [NQ, CS, D]
    float* out = (float*)d_out;                // [B*D*T] q_sum ++ [B] loss_sum

    // workspace: cn[8192] f32 | part[256] f32 | cbS 2-plane f16 (4 MB)
    float*    cn   = (float*)d_ws;
    float*    part = cn + NQn * CSc;
    _Float16* cbS  = (_Float16*)(part + 256);

    split_kernel<<<(NQn * CSc) / 64, 64, 0, stream>>>(cb, cbS, cn);

    const int nblocks = (Bb * Tt) / TB;  // 256
    rvq_mfma<<<nblocks, 512, 0, stream>>>(x, cb, cbS, cn, out, part);

    loss_kernel<<<1, 64, 0, stream>>>(part, out + (size_t)Bb * Dd * Tt);
}